// Round 6
// baseline (366.531 us; speedup 1.0000x reference)
//
#include <hip/hip_runtime.h>
#include <hip/hip_bf16.h>
#include <cstdint>
#include <cstddef>

// B=4, LQ=LK=1024, D=512, H=8. fp32 in/out; bf16 MFMA compute.
// R6: U_h = Wp_h.Wv_h precompute kills the v projection (17 GFLOP);
// mask bit-packed (16.8MB -> 512KB) for the scores epilogue.

typedef __bf16 bf16;
typedef __bf16 bf16x4 __attribute__((ext_vector_type(4)));
typedef __bf16 bf16x8 __attribute__((ext_vector_type(8)));
typedef float f32x4 __attribute__((ext_vector_type(4)));

__device__ inline void gload_lds16(const void* g, void* l) {
  __builtin_amdgcn_global_load_lds(
      (const __attribute__((address_space(1))) void*)g,
      (__attribute__((address_space(3))) void*)l, 16, 0, 0);
}

// Convert five fp32 tensors (2M elements each) to bf16. grid: (2048, 5).
__global__ __launch_bounds__(256) void cvt5(
    const float* __restrict__ s0, const float* __restrict__ s1,
    const float* __restrict__ s2, const float* __restrict__ s3,
    const float* __restrict__ s4,
    bf16* __restrict__ d0, bf16* __restrict__ d1, bf16* __restrict__ d2,
    bf16* __restrict__ d3, bf16* __restrict__ d4)
{
  const float* s; bf16* d;
  switch (blockIdx.y) {
    case 0: s = s0; d = d0; break;
    case 1: s = s1; d = d1; break;
    case 2: s = s2; d = d2; break;
    case 3: s = s3; d = d3; break;
    default: s = s4; d = d4; break;
  }
  const int i = (blockIdx.x * 256 + threadIdx.x) * 4;
  float4 v = *(const float4*)(s + i);
  bf16x4 o;
  o[0] = (bf16)v.x; o[1] = (bf16)v.y; o[2] = (bf16)v.z; o[3] = (bf16)v.w;
  *(bf16x4*)(d + i) = o;
}

// WvT[h][d][e'] = (bf16) Wv[h][e'][d].  grid 2048 x 256.
__global__ __launch_bounds__(256) void cvtT(
    const float* __restrict__ Wv, bf16* __restrict__ WvT)
{
  const int gid = blockIdx.x * 256 + threadIdx.x;   // [0, 524288)
  const int e0 = (gid & 127) * 4;
  const int d = (gid >> 7) & 511;
  const int h = gid >> 16;
  const float* src = Wv + (size_t)h * 262144 + (size_t)e0 * 512 + d;
  bf16x4 o;
  o[0] = (bf16)src[0];
  o[1] = (bf16)src[512];
  o[2] = (bf16)src[1024];
  o[3] = (bf16)src[1536];
  *(bf16x4*)(WvT + (size_t)h * 262144 + (size_t)d * 512 + e0) = o;
}

// mask [4,1024,1024] i32 -> bits [4,1024,32] u32. grid 512 x 256.
__global__ __launch_bounds__(256) void pack_mask(
    const int* __restrict__ m, unsigned* __restrict__ mb)
{
  const int gid = blockIdx.x * 256 + threadIdx.x;   // [0, 131072)
  const int* src = m + (size_t)gid * 32;
  unsigned bits = 0;
#pragma unroll
  for (int j = 0; j < 32; j += 4) {
    int4 v = *(const int4*)(src + j);
    if (v.x) bits |= 1u << j;
    if (v.y) bits |= 1u << (j + 1);
    if (v.z) bits |= 1u << (j + 2);
    if (v.w) bits |= 1u << (j + 3);
  }
  mb[gid] = bits;
}

// Tile body: C[128,128] at (m0,n0) of scale*(A . B^T). BK=64, 256 thr.
// LDS swizzle: global 16B-chunk c of row r lives at slot c ^ (r&7).
// MODE 0: C = acc*scale (CT).
// MODE 1: P = maskbit ? exp(acc*scale) : 0 -> C (bf16); atomicAdd row sums.
template <typename CT, int MODE>
__device__ __forceinline__ void gemm_body(
    bf16* As, bf16* Bs,
    const bf16* __restrict__ A, const bf16* __restrict__ B, CT* __restrict__ C,
    int K, int lda, int ldb, int ldc, int m0, int n0, float scale,
    const unsigned* __restrict__ mrow, float* __restrict__ sumrow)
{
  const int t = threadIdx.x;
  const int lane = t & 63, w = t >> 6;
  const int wm = w >> 1, wn = w & 1;

  const int srow = t >> 3;                       // 0..31
  const int schunk = (t & 7) ^ (srow & 7);       // swizzled source chunk
  const bf16* Ag = A + (size_t)(m0 + srow) * lda + schunk * 8;
  const bf16* Bg = B + (size_t)(n0 + srow) * ldb + schunk * 8;
  bf16* Als = As + t * 8;
  bf16* Bls = Bs + t * 8;

  f32x4 acc[4][4] = {};
  const int rr = lane & 15;
  const int q4 = lane >> 4;

  const int kIters = K >> 6;
  for (int kt = 0; kt < kIters; ++kt) {
    __syncthreads();
#pragma unroll
    for (int i = 0; i < 4; ++i) {
      gload_lds16(Ag + (size_t)(32 * i) * lda, Als + i * 2048);
      gload_lds16(Bg + (size_t)(32 * i) * ldb, Bls + i * 2048);
    }
    Ag += 64; Bg += 64;
    __syncthreads();

#pragma unroll
    for (int kk = 0; kk < 2; ++kk) {
      bf16x8 af[4], bfr[4];
      const int ck = kk * 4 + q4;
#pragma unroll
      for (int r = 0; r < 4; ++r) {
        const int R = wm * 64 + r * 16 + rr;
        af[r] = *(const bf16x8*)(As + R * 64 + ((ck ^ (R & 7)) << 3));
      }
#pragma unroll
      for (int c = 0; c < 4; ++c) {
        const int R = wn * 64 + c * 16 + rr;
        bfr[c] = *(const bf16x8*)(Bs + R * 64 + ((ck ^ (R & 7)) << 3));
      }
#pragma unroll
      for (int r = 0; r < 4; ++r)
#pragma unroll
        for (int c = 0; c < 4; ++c)
          acc[r][c] = __builtin_amdgcn_mfma_f32_16x16x32_bf16(af[r], bfr[c], acc[r][c], 0, 0, 0);
    }
  }

  // C/D frag: col = lane&15, row = (lane>>4)*4 + reg
  if (MODE == 0) {
#pragma unroll
    for (int r = 0; r < 4; ++r) {
#pragma unroll
      for (int c = 0; c < 4; ++c) {
        const int gr0 = m0 + wm * 64 + r * 16 + (q4 << 2);
        const int gc = n0 + wn * 64 + c * 16 + rr;
#pragma unroll
        for (int i = 0; i < 4; ++i)
          C[(size_t)(gr0 + i) * ldc + gc] = (CT)(acc[r][c][i] * scale);
      }
    }
  } else {
    const int cb0 = (n0 + wn * 64) >> 5;
#pragma unroll
    for (int r = 0; r < 4; ++r) {
#pragma unroll
      for (int i = 0; i < 4; ++i) {
        const int row = m0 + wm * 64 + r * 16 + (q4 << 2) + i;
        const unsigned mw0 = mrow[(row << 5) + cb0];
        const unsigned mw1 = mrow[(row << 5) + cb0 + 1];
        float ps = 0.0f;
#pragma unroll
        for (int c = 0; c < 4; ++c) {
          const int gc = n0 + wn * 64 + c * 16 + rr;
          const unsigned mw = (c >= 2) ? mw1 : mw0;
          const unsigned bit = (mw >> (((c & 1) << 4) + rr)) & 1u;
          float p = bit ? __expf(acc[r][c][i] * scale) : 0.0f;
          C[(size_t)row * ldc + gc] = (CT)p;
          ps += p;
        }
        ps += __shfl_xor(ps, 1); ps += __shfl_xor(ps, 2);
        ps += __shfl_xor(ps, 4); ps += __shfl_xor(ps, 8);
        if (rr == 0) atomicAdd(sumrow + row, ps);
      }
    }
  }
}

// Generic batched NT GEMM: z = b*8+h with per-operand b/h strides.
template <typename CT, int MODE>
__global__ __launch_bounds__(256) void gemm_nt(
    const bf16* __restrict__ A, const bf16* __restrict__ B, CT* __restrict__ C,
    int K, int lda, int ldb, int ldc,
    long ab, long ah, long bbs, long bh, long cb, long ch, float scale,
    const unsigned* __restrict__ mbits, float* __restrict__ sums)
{
  __shared__ bf16 As[128 * 64];
  __shared__ bf16 Bs[128 * 64];
  const int z = blockIdx.z;
  const int zb = z >> 3, zh = z & 7;
  A += (size_t)zb * ab + (size_t)zh * ah;
  B += (size_t)zb * bbs + (size_t)zh * bh;
  C += (size_t)zb * cb + (size_t)zh * ch;
  const unsigned* mrow = (MODE == 1) ? mbits + ((size_t)zb << 15) : nullptr;
  float* sumrow = (MODE == 1) ? sums + ((size_t)z << 10) : nullptr;
  gemm_body<CT, MODE>(As, Bs, A, B, C, K, lda, ldb, ldc,
                      blockIdx.y * 128, blockIdx.x * 128, scale, mrow, sumrow);
}

// Fused q/k projections (M=1024,N=512,K=512). grid (32, 32, 2).
__global__ __launch_bounds__(256) void qkv_kernel(
    const bf16* __restrict__ xb, const bf16* __restrict__ stb,
    const bf16* __restrict__ wqb, const bf16* __restrict__ wkb,
    bf16* __restrict__ q, bf16* __restrict__ k)
{
  __shared__ bf16 As[128 * 64];
  __shared__ bf16 Bs[128 * 64];
  const int tile = blockIdx.x;
  const int zz = blockIdx.y;
  const int job = blockIdx.z;
  const size_t zb = zz >> 3, zh = zz & 7;
  const bf16* Ain = (job == 0) ? xb : stb;
  const bf16* W = (job == 0) ? wqb : wkb;
  bf16* Cout = (job == 0) ? q : k;
  gemm_body<bf16, 0>(As, Bs, Ain + zb * 524288, W + zh * 262144,
      Cout + zb * 4194304 + zh * 524288, 512, 512, 512, 512,
      (tile >> 2) * 128, (tile & 3) * 128, 1.0f, nullptr, nullptr);
}

// out_part[hp] = sum_{h in pair} sinv_h ⊙ (P_h · VWT_h^T).
// grid (4 e-tiles, 8 l-tiles, 16 = b*4+hp). fp32 out.
__global__ __launch_bounds__(256) void pvw_kernel(
    const bf16* __restrict__ P, const bf16* __restrict__ VWT,
    const float* __restrict__ sums, float* __restrict__ part)
{
  __shared__ bf16 As[128 * 64];
  __shared__ bf16 Bs[128 * 64];
  const int z = blockIdx.z;
  const int zb = z >> 2, hp = z & 3;
  const int m0 = blockIdx.y * 128, n0 = blockIdx.x * 128;
  const int t = threadIdx.x;
  const int lane = t & 63, w = t >> 6;
  const int wm = w >> 1, wn = w & 1;
  const int srow = t >> 3, schunk = (t & 7) ^ (srow & 7);
  const int rr = lane & 15, q4 = lane >> 4;
  bf16* Als = As + t * 8;
  bf16* Bls = Bs + t * 8;

  f32x4 accO[4][4] = {};

#pragma unroll
  for (int hh = 0; hh < 2; ++hh) {
    const int h = hp * 2 + hh;
    const bf16* Ag = P + (size_t)zb * 8388608 + (size_t)h * 1048576
                       + (size_t)(m0 + srow) * 1024 + schunk * 8;
    const bf16* Bg = VWT + (size_t)zb * 4194304 + (size_t)h * 524288
                        + (size_t)(n0 + srow) * 1024 + schunk * 8;
    f32x4 acc[4][4] = {};
    for (int kt = 0; kt < 16; ++kt) {
      __syncthreads();
#pragma unroll
      for (int i = 0; i < 4; ++i) {
        gload_lds16(Ag + (size_t)(32 * i) * 1024, Als + i * 2048);
        gload_lds16(Bg + (size_t)(32 * i) * 1024, Bls + i * 2048);
      }
      Ag += 64; Bg += 64;
      __syncthreads();
#pragma unroll
      for (int kk = 0; kk < 2; ++kk) {
        bf16x8 af[4], bfr[4];
        const int ck = kk * 4 + q4;
#pragma unroll
        for (int r = 0; r < 4; ++r) {
          const int R = wm * 64 + r * 16 + rr;
          af[r] = *(const bf16x8*)(As + R * 64 + ((ck ^ (R & 7)) << 3));
        }
#pragma unroll
        for (int c = 0; c < 4; ++c) {
          const int R = wn * 64 + c * 16 + rr;
          bfr[c] = *(const bf16x8*)(Bs + R * 64 + ((ck ^ (R & 7)) << 3));
        }
#pragma unroll
        for (int r = 0; r < 4; ++r)
#pragma unroll
          for (int c = 0; c < 4; ++c)
            acc[r][c] = __builtin_amdgcn_mfma_f32_16x16x32_bf16(af[r], bfr[c], acc[r][c], 0, 0, 0);
      }
    }
    // per-h normalization, accumulate into output accumulator
    const float* srs = sums + ((size_t)zb * 8 + h) * 1024;
#pragma unroll
    for (int r = 0; r < 4; ++r) {
#pragma unroll
      for (int i = 0; i < 4; ++i) {
        const float inv = 1.0f / srs[m0 + wm * 64 + r * 16 + (q4 << 2) + i];
#pragma unroll
        for (int c = 0; c < 4; ++c)
          accO[r][c][i] += acc[r][c][i] * inv;
      }
    }
  }

  float* Cp = part + (size_t)hp * 2097152 + (size_t)zb * 524288;
#pragma unroll
  for (int r = 0; r < 4; ++r) {
#pragma unroll
    for (int c = 0; c < 4; ++c) {
      const int gr0 = m0 + wm * 64 + r * 16 + (q4 << 2);
      const int gc = n0 + wn * 64 + c * 16 + rr;
#pragma unroll
      for (int i = 0; i < 4; ++i)
        Cp[(size_t)(gr0 + i) * 512 + gc] = accO[r][c][i];
    }
  }
}

// out = part0+part1+part2+part3 (fp32, 2M elems). grid 2048 x 256.
__global__ __launch_bounds__(256) void reduce4(
    const float* __restrict__ part, float* __restrict__ out)
{
  const size_t i = ((size_t)blockIdx.x * 256 + threadIdx.x) * 4;
  float4 a = *(const float4*)(part + i);
  float4 b = *(const float4*)(part + 2097152 + i);
  float4 c = *(const float4*)(part + 4194304 + i);
  float4 d = *(const float4*)(part + 6291456 + i);
  float4 o;
  o.x = (a.x + b.x) + (c.x + d.x);
  o.y = (a.y + b.y) + (c.y + d.y);
  o.z = (a.z + b.z) + (c.z + d.z);
  o.w = (a.w + b.w) + (c.w + d.w);
  *(float4*)(out + i) = o;
}

extern "C" void kernel_launch(void* const* d_in, const int* in_sizes, int n_in,
                              void* d_out, int out_size, void* d_ws, size_t ws_size,
                              hipStream_t stream) {
  const float* x    = (const float*)d_in[0];
  const float* st   = (const float*)d_in[1];
  const int*   mask = (const int*)d_in[2];
  const float* Wq   = (const float*)d_in[3];
  const float* Wk   = (const float*)d_in[4];
  const float* Wv   = (const float*)d_in[5];
  const float* Wp   = (const float*)d_in[6];
  float* out = (float*)d_out;

  char* ws = (char*)d_ws;
  const size_t MB = 1048576;
  bf16* xb  = (bf16*)(ws);               // 4MB
  bf16* stb = (bf16*)(ws + 4 * MB);      // 4MB (live through VWT')
  bf16* wqb = (bf16*)(ws + 8 * MB);      // 4MB; dead after qkv -> mbits overlays
  bf16* wkb = (bf16*)(ws + 12 * MB);     // 4MB; dead after qkv -> sums overlays
  bf16* wpb = (bf16*)(ws + 16 * MB);     // 4MB
  bf16* WvT = (bf16*)(ws + 20 * MB);     // 4MB [8,512,512] transposed
  bf16* U   = (bf16*)(ws + 24 * MB);     // 4MB [8,512,512] Wp_h.Wv_h
  bf16* q   = (bf16*)(ws + 28 * MB);     // 32MB; dead after scores -> part overlays
  bf16* k   = (bf16*)(ws + 60 * MB);     // 32MB
  bf16* VWT = (bf16*)(ws + 92 * MB);     // 32MB [4,8,512,1024]
  bf16* sc  = (bf16*)(ws + 124 * MB);    // 64MB P = exp(scores)
  unsigned* mbits = (unsigned*)(ws + 8 * MB);   // 512KB (over wqb)
  float*    sums  = (float*)(ws + 12 * MB);     // 128KB (over wkb)
  float*    part  = (float*)(ws + 28 * MB);     // 32MB fp32 (over q)

  dim3 blk(256);
  const float scale = 0.04419417382415922f;  // 1/sqrt(512)

  cvt5<<<dim3(2048, 5), blk, 0, stream>>>(x, st, Wq, Wk, Wp,
                                          xb, stb, wqb, wkb, wpb);
  cvtT<<<dim3(2048), blk, 0, stream>>>(Wv, WvT);

  // U_h = Wp_h . WvT_h^T  (M=512,N=512,K=512), z = h
  gemm_nt<bf16, 0><<<dim3(4, 4, 8), blk, 0, stream>>>(wpb, WvT, U,
      512, 4096, 512, 512, 0L, 512L, 0L, 262144L, 0L, 262144L, 1.0f,
      nullptr, nullptr);

  // q/k projections (2048 blocks)
  qkv_kernel<<<dim3(32, 32, 2), blk, 0, stream>>>(xb, stb, wqb, wkb, q, k);

  // mask bits + zero row-sums (wqb/wkb regions dead now)
  pack_mask<<<dim3(512), blk, 0, stream>>>(mask, mbits);
  hipMemsetAsync(sums, 0, 32 * 1024 * sizeof(float), stream);

  // VWT[b,h] = U_h . states_b^T  (M=512,N=1024,K=512)
  gemm_nt<bf16, 0><<<dim3(8, 4, 32), blk, 0, stream>>>(U, stb, VWT,
      512, 512, 512, 1024, 0L, 262144L, 524288L, 0L, 4194304L, 524288L, 1.0f,
      nullptr, nullptr);

  // P = maskbit ? exp(scale * q.k^T) : 0; rowsums via atomics. (M=N=1024,K=512)
  gemm_nt<bf16, 1><<<dim3(8, 8, 32), blk, 0, stream>>>(q, k, sc,
      512, 512, 512, 1024, 4194304L, 524288L, 4194304L, 524288L,
      8388608L, 1048576L, scale, mbits, sums);

  // out partials: sum over h-pairs of sinv ⊙ (P_h . VWT_h^T)
  pvw_kernel<<<dim3(4, 8, 16), blk, 0, stream>>>(sc, VWT, sums, part);

  // out = sum of 4 partials
  reduce4<<<dim3(2048), blk, 0, stream>>>(part, out);
}

// Round 7
// 275.807 us; speedup vs baseline: 1.3289x; 1.3289x over previous
//
#include <hip/hip_runtime.h>
#include <hip/hip_bf16.h>
#include <cstdint>
#include <cstddef>

// B=4, LQ=LK=1024, D=512, H=8. fp32 in/out; bf16 MFMA compute.
// R7: 5-dispatch consolidation (prep / proj / big / pvw / reduce) +
// XCD-aware block swizzle so same-z blocks share one XCD's L2.

typedef __bf16 bf16;
typedef __bf16 bf16x4 __attribute__((ext_vector_type(4)));
typedef __bf16 bf16x8 __attribute__((ext_vector_type(8)));
typedef float f32x4 __attribute__((ext_vector_type(4)));

__device__ inline void gload_lds16(const void* g, void* l) {
  __builtin_amdgcn_global_load_lds(
      (const __attribute__((address_space(1))) void*)g,
      (__attribute__((address_space(3))) void*)l, 16, 0, 0);
}

// Tile body: C[128,128] at (m0,n0) of scale*(A . B^T). BK=64, 256 thr.
// LDS swizzle: global 16B-chunk c of row r lives at slot c ^ (r&7).
// MODE 0: C = acc*scale (CT).
// MODE 1: P = maskbit ? exp(acc*scale) : 0 -> C (bf16); atomicAdd row sums.
template <typename CT, int MODE>
__device__ __forceinline__ void gemm_body(
    bf16* As, bf16* Bs,
    const bf16* __restrict__ A, const bf16* __restrict__ B, CT* __restrict__ C,
    int K, int lda, int ldb, int ldc, int m0, int n0, float scale,
    const unsigned* __restrict__ mrow, float* __restrict__ sumrow)
{
  const int t = threadIdx.x;
  const int lane = t & 63, w = t >> 6;
  const int wm = w >> 1, wn = w & 1;

  const int srow = t >> 3;                       // 0..31
  const int schunk = (t & 7) ^ (srow & 7);       // swizzled source chunk
  const bf16* Ag = A + (size_t)(m0 + srow) * lda + schunk * 8;
  const bf16* Bg = B + (size_t)(n0 + srow) * ldb + schunk * 8;
  bf16* Als = As + t * 8;
  bf16* Bls = Bs + t * 8;

  f32x4 acc[4][4] = {};
  const int rr = lane & 15;
  const int q4 = lane >> 4;

  const int kIters = K >> 6;
  for (int kt = 0; kt < kIters; ++kt) {
    __syncthreads();
#pragma unroll
    for (int i = 0; i < 4; ++i) {
      gload_lds16(Ag + (size_t)(32 * i) * lda, Als + i * 2048);
      gload_lds16(Bg + (size_t)(32 * i) * ldb, Bls + i * 2048);
    }
    Ag += 64; Bg += 64;
    __syncthreads();

#pragma unroll
    for (int kk = 0; kk < 2; ++kk) {
      bf16x8 af[4], bfr[4];
      const int ck = kk * 4 + q4;
#pragma unroll
      for (int r = 0; r < 4; ++r) {
        const int R = wm * 64 + r * 16 + rr;
        af[r] = *(const bf16x8*)(As + R * 64 + ((ck ^ (R & 7)) << 3));
      }
#pragma unroll
      for (int c = 0; c < 4; ++c) {
        const int R = wn * 64 + c * 16 + rr;
        bfr[c] = *(const bf16x8*)(Bs + R * 64 + ((ck ^ (R & 7)) << 3));
      }
#pragma unroll
      for (int r = 0; r < 4; ++r)
#pragma unroll
        for (int c = 0; c < 4; ++c)
          acc[r][c] = __builtin_amdgcn_mfma_f32_16x16x32_bf16(af[r], bfr[c], acc[r][c], 0, 0, 0);
    }
  }

  // C/D frag: col = lane&15, row = (lane>>4)*4 + reg
  if (MODE == 0) {
#pragma unroll
    for (int r = 0; r < 4; ++r) {
#pragma unroll
      for (int c = 0; c < 4; ++c) {
        const int gr0 = m0 + wm * 64 + r * 16 + (q4 << 2);
        const int gc = n0 + wn * 64 + c * 16 + rr;
#pragma unroll
        for (int i = 0; i < 4; ++i)
          C[(size_t)(gr0 + i) * ldc + gc] = (CT)(acc[r][c][i] * scale);
      }
    }
  } else {
    const int cb0 = (n0 + wn * 64) >> 5;
#pragma unroll
    for (int r = 0; r < 4; ++r) {
#pragma unroll
      for (int i = 0; i < 4; ++i) {
        const int row = m0 + wm * 64 + r * 16 + (q4 << 2) + i;
        const unsigned mw0 = mrow[(row << 5) + cb0];
        const unsigned mw1 = mrow[(row << 5) + cb0 + 1];
        float ps = 0.0f;
#pragma unroll
        for (int c = 0; c < 4; ++c) {
          const int gc = n0 + wn * 64 + c * 16 + rr;
          const unsigned mw = (c >= 2) ? mw1 : mw0;
          const unsigned bit = (mw >> (((c & 1) << 4) + rr)) & 1u;
          float p = bit ? __expf(acc[r][c][i] * scale) : 0.0f;
          C[(size_t)row * ldc + gc] = (CT)p;
          ps += p;
        }
        ps += __shfl_xor(ps, 1); ps += __shfl_xor(ps, 2);
        ps += __shfl_xor(ps, 4); ps += __shfl_xor(ps, 8);
        if (rr == 0) atomicAdd(sumrow + row, ps);
      }
    }
  }
}

// ---- Dispatch 1: prep (cvt5 + cvtT + pack_mask + zero sums). grid 12832. ----
__global__ __launch_bounds__(256) void prep_kernel(
    const float* __restrict__ x, const float* __restrict__ st,
    const float* __restrict__ Wq, const float* __restrict__ Wk,
    const float* __restrict__ Wp, const float* __restrict__ Wv,
    const int* __restrict__ mask,
    bf16* __restrict__ xb, bf16* __restrict__ stb, bf16* __restrict__ wqb,
    bf16* __restrict__ wkb, bf16* __restrict__ wpb, bf16* __restrict__ WvT,
    unsigned* __restrict__ mbits, float* __restrict__ sums)
{
  const int lin = blockIdx.x;
  const int t = threadIdx.x;
  if (lin < 10240) {
    const float* s; bf16* d;
    switch (lin >> 11) {
      case 0: s = x; d = xb; break;
      case 1: s = st; d = stb; break;
      case 2: s = Wq; d = wqb; break;
      case 3: s = Wk; d = wkb; break;
      default: s = Wp; d = wpb; break;
    }
    const int i = ((lin & 2047) * 256 + t) * 4;
    float4 v = *(const float4*)(s + i);
    bf16x4 o;
    o[0] = (bf16)v.x; o[1] = (bf16)v.y; o[2] = (bf16)v.z; o[3] = (bf16)v.w;
    *(bf16x4*)(d + i) = o;
  } else if (lin < 12288) {
    // WvT[h][d][e'] = Wv[h][e'][d]
    const int gid = (lin - 10240) * 256 + t;      // [0, 524288)
    const int e0 = (gid & 127) * 4;
    const int d = (gid >> 7) & 511;
    const int h = gid >> 16;
    const float* src = Wv + (size_t)h * 262144 + (size_t)e0 * 512 + d;
    bf16x4 o;
    o[0] = (bf16)src[0];
    o[1] = (bf16)src[512];
    o[2] = (bf16)src[1024];
    o[3] = (bf16)src[1536];
    *(bf16x4*)(WvT + (size_t)h * 262144 + (size_t)d * 512 + e0) = o;
  } else if (lin < 12800) {
    const int gid = (lin - 12288) * 256 + t;      // [0, 131072)
    const int* src = mask + (size_t)gid * 32;
    unsigned bits = 0;
#pragma unroll
    for (int j = 0; j < 32; j += 4) {
      int4 v = *(const int4*)(src + j);
      if (v.x) bits |= 1u << j;
      if (v.y) bits |= 1u << (j + 1);
      if (v.z) bits |= 1u << (j + 2);
      if (v.w) bits |= 1u << (j + 3);
    }
    mbits[gid] = bits;
  } else {
    const int i = ((lin - 12800) * 256 + t) * 4;  // [0, 32768) floats
    *(float4*)(sums + i) = make_float4(0.f, 0.f, 0.f, 0.f);
  }
}

// ---- Dispatch 2: proj (q/k projections + U = Wp_h.Wv_h). grid 2176. ----
__global__ __launch_bounds__(256) void proj_kernel(
    const bf16* __restrict__ xb, const bf16* __restrict__ stb,
    const bf16* __restrict__ wqb, const bf16* __restrict__ wkb,
    const bf16* __restrict__ wpb, const bf16* __restrict__ WvT,
    bf16* __restrict__ q, bf16* __restrict__ k, bf16* __restrict__ U)
{
  __shared__ bf16 As[128 * 64];
  __shared__ bf16 Bs[128 * 64];
  const int lin = blockIdx.x;
  if (lin < 2048) {
    // XCD swizzle: g = job*32+zz grouped per XCD
    const int g = ((lin >> 8) << 3) | (lin & 7);   // [0,64)
    const int tile = (lin >> 3) & 31;
    const int job = g >> 5;
    const int zz = g & 31;
    const size_t zb = zz >> 3, zh = zz & 7;
    const bf16* Ain = (job == 0) ? xb : stb;
    const bf16* W = (job == 0) ? wqb : wkb;
    bf16* Cout = (job == 0) ? q : k;
    gemm_body<bf16, 0>(As, Bs, Ain + zb * 524288, W + zh * 262144,
        Cout + zb * 4194304 + zh * 524288, 512, 512, 512, 512,
        (tile >> 2) * 128, (tile & 3) * 128, 1.0f, nullptr, nullptr);
  } else {
    // U_h[e,d] = sum_e' Wp[e, h*512+e'] * WvT_h[d, e']
    const int lin2 = lin - 2048;                   // [0,128)
    const int h = lin2 >> 4;
    const int tile = lin2 & 15;
    gemm_body<bf16, 0>(As, Bs, wpb + (size_t)h * 512, WvT + (size_t)h * 262144,
        U + (size_t)h * 262144, 512, 4096, 512, 512,
        (tile >> 2) * 128, (tile & 3) * 128, 1.0f, nullptr, nullptr);
  }
}

// ---- Dispatch 3: big (scores+exp+rowsum, and VWT = U.states^T). grid 3072. ----
__global__ __launch_bounds__(256) void big_kernel(
    const bf16* __restrict__ q, const bf16* __restrict__ k,
    const bf16* __restrict__ U, const bf16* __restrict__ stb,
    bf16* __restrict__ P, bf16* __restrict__ VWT,
    const unsigned* __restrict__ mbits, float* __restrict__ sums, float scale)
{
  __shared__ bf16 As[128 * 64];
  __shared__ bf16 Bs[128 * 64];
  const int lin = blockIdx.x;
  if (lin < 2048) {
    // scores: z in [0,32), 64 tiles (8x8); same-z blocks on one XCD
    const int z = ((lin >> 9) << 3) | (lin & 7);
    const int j = (lin >> 3) & 63;
    const int zb = z >> 3, zh = z & 7;
    const bf16* A = q + (size_t)zb * 4194304 + (size_t)zh * 524288;
    const bf16* B = k + (size_t)zb * 4194304 + (size_t)zh * 524288;
    bf16* C = P + (size_t)zb * 8388608 + (size_t)zh * 1048576;
    const unsigned* mrow = mbits + ((size_t)zb << 15);
    float* sumrow = sums + ((size_t)z << 10);
    gemm_body<bf16, 1>(As, Bs, A, B, C, 512, 512, 512, 1024,
                       (j >> 3) * 128, (j & 7) * 128, scale, mrow, sumrow);
  } else {
    // VWT[b,h][e,s] = U_h . states_b^T : z in [0,32), 32 tiles (8 n x 4 m)
    const int lin2 = lin - 2048;
    const int z = ((lin2 >> 8) << 3) | (lin2 & 7);
    const int j = (lin2 >> 3) & 31;
    const int zb = z >> 3, zh = z & 7;
    gemm_body<bf16, 0>(As, Bs, U + (size_t)zh * 262144, stb + (size_t)zb * 524288,
        VWT + (size_t)zb * 4194304 + (size_t)zh * 524288, 512, 512, 512, 1024,
        (j >> 3) * 128, (j & 7) * 128, 1.0f, nullptr, nullptr);
  }
}

// ---- Dispatch 4: pvw — out_part[hp] = sum_{h in pair} sinv_h ⊙ (P_h·VWT_h^T).
// grid 512 (swizzled: z in [0,16), 32 tiles = 8 l x 4 e). fp32 out. ----
__global__ __launch_bounds__(256) void pvw_kernel(
    const bf16* __restrict__ P, const bf16* __restrict__ VWT,
    const float* __restrict__ sums, float* __restrict__ part)
{
  __shared__ bf16 As[128 * 64];
  __shared__ bf16 Bs[128 * 64];
  const int lin = blockIdx.x;
  const int z = ((lin >> 8) << 3) | (lin & 7);    // [0,16)
  const int j = (lin >> 3) & 31;
  const int zb = z >> 2, hp = z & 3;
  const int m0 = (j >> 2) * 128, n0 = (j & 3) * 128;
  const int t = threadIdx.x;
  const int lane = t & 63, w = t >> 6;
  const int wm = w >> 1, wn = w & 1;
  const int srow = t >> 3, schunk = (t & 7) ^ (srow & 7);
  const int rr = lane & 15, q4 = lane >> 4;
  bf16* Als = As + t * 8;
  bf16* Bls = Bs + t * 8;

  f32x4 accO[4][4] = {};

#pragma unroll
  for (int hh = 0; hh < 2; ++hh) {
    const int h = hp * 2 + hh;
    const bf16* Ag = P + (size_t)zb * 8388608 + (size_t)h * 1048576
                       + (size_t)(m0 + srow) * 1024 + schunk * 8;
    const bf16* Bg = VWT + (size_t)zb * 4194304 + (size_t)h * 524288
                        + (size_t)(n0 + srow) * 1024 + schunk * 8;
    f32x4 acc[4][4] = {};
    for (int kt = 0; kt < 16; ++kt) {
      __syncthreads();
#pragma unroll
      for (int i = 0; i < 4; ++i) {
        gload_lds16(Ag + (size_t)(32 * i) * 1024, Als + i * 2048);
        gload_lds16(Bg + (size_t)(32 * i) * 1024, Bls + i * 2048);
      }
      Ag += 64; Bg += 64;
      __syncthreads();
#pragma unroll
      for (int kk = 0; kk < 2; ++kk) {
        bf16x8 af[4], bfr[4];
        const int ck = kk * 4 + q4;
#pragma unroll
        for (int r = 0; r < 4; ++r) {
          const int R = wm * 64 + r * 16 + rr;
          af[r] = *(const bf16x8*)(As + R * 64 + ((ck ^ (R & 7)) << 3));
        }
#pragma unroll
        for (int c = 0; c < 4; ++c) {
          const int R = wn * 64 + c * 16 + rr;
          bfr[c] = *(const bf16x8*)(Bs + R * 64 + ((ck ^ (R & 7)) << 3));
        }
#pragma unroll
        for (int r = 0; r < 4; ++r)
#pragma unroll
          for (int c = 0; c < 4; ++c)
            acc[r][c] = __builtin_amdgcn_mfma_f32_16x16x32_bf16(af[r], bfr[c], acc[r][c], 0, 0, 0);
      }
    }
    const float* srs = sums + ((size_t)zb * 8 + h) * 1024;
#pragma unroll
    for (int r = 0; r < 4; ++r) {
#pragma unroll
      for (int i = 0; i < 4; ++i) {
        const float inv = 1.0f / srs[m0 + wm * 64 + r * 16 + (q4 << 2) + i];
#pragma unroll
        for (int c = 0; c < 4; ++c)
          accO[r][c][i] += acc[r][c][i] * inv;
      }
    }
  }

  float* Cp = part + (size_t)hp * 2097152 + (size_t)zb * 524288;
#pragma unroll
  for (int r = 0; r < 4; ++r) {
#pragma unroll
    for (int c = 0; c < 4; ++c) {
      const int gr0 = m0 + wm * 64 + r * 16 + (q4 << 2);
      const int gc = n0 + wn * 64 + c * 16 + rr;
#pragma unroll
      for (int i = 0; i < 4; ++i)
        Cp[(size_t)(gr0 + i) * 512 + gc] = accO[r][c][i];
    }
  }
}

// ---- Dispatch 5: out = part0+part1+part2+part3. grid 2048. ----
__global__ __launch_bounds__(256) void reduce4(
    const float* __restrict__ part, float* __restrict__ out)
{
  const size_t i = ((size_t)blockIdx.x * 256 + threadIdx.x) * 4;
  float4 a = *(const float4*)(part + i);
  float4 b = *(const float4*)(part + 2097152 + i);
  float4 c = *(const float4*)(part + 4194304 + i);
  float4 d = *(const float4*)(part + 6291456 + i);
  float4 o;
  o.x = (a.x + b.x) + (c.x + d.x);
  o.y = (a.y + b.y) + (c.y + d.y);
  o.z = (a.z + b.z) + (c.z + d.z);
  o.w = (a.w + b.w) + (c.w + d.w);
  *(float4*)(out + i) = o;
}

extern "C" void kernel_launch(void* const* d_in, const int* in_sizes, int n_in,
                              void* d_out, int out_size, void* d_ws, size_t ws_size,
                              hipStream_t stream) {
  const float* x    = (const float*)d_in[0];
  const float* st   = (const float*)d_in[1];
  const int*   mask = (const int*)d_in[2];
  const float* Wq   = (const float*)d_in[3];
  const float* Wk   = (const float*)d_in[4];
  const float* Wv   = (const float*)d_in[5];
  const float* Wp   = (const float*)d_in[6];
  float* out = (float*)d_out;

  char* ws = (char*)d_ws;
  const size_t MB = 1048576;
  bf16* xb  = (bf16*)(ws);               // 4MB
  bf16* stb = (bf16*)(ws + 4 * MB);      // 4MB (live through VWT)
  bf16* wqb = (bf16*)(ws + 8 * MB);      // 4MB
  bf16* wkb = (bf16*)(ws + 12 * MB);     // 4MB
  bf16* wpb = (bf16*)(ws + 16 * MB);     // 4MB
  bf16* WvT = (bf16*)(ws + 20 * MB);     // 4MB [8,512,512] transposed
  bf16* U   = (bf16*)(ws + 24 * MB);     // 4MB [8,512,512] Wp_h.Wv_h
  bf16* q   = (bf16*)(ws + 28 * MB);     // 32MB; dead after scores -> part overlays
  bf16* k   = (bf16*)(ws + 60 * MB);     // 32MB
  bf16* VWT = (bf16*)(ws + 92 * MB);     // 32MB [4,8,512,1024]
  bf16* sc  = (bf16*)(ws + 124 * MB);    // 64MB P = exp(scores)
  unsigned* mbits = (unsigned*)(ws + 188 * MB);  // 512KB
  float*    sums  = (float*)(ws + 189 * MB);     // 128KB
  float*    part  = (float*)(ws + 28 * MB);      // 32MB fp32 (over q)

  dim3 blk(256);
  const float scale = 0.04419417382415922f;  // 1/sqrt(512)

  prep_kernel<<<dim3(12832), blk, 0, stream>>>(x, st, Wq, Wk, Wp, Wv, mask,
      xb, stb, wqb, wkb, wpb, WvT, mbits, sums);

  proj_kernel<<<dim3(2176), blk, 0, stream>>>(xb, stb, wqb, wkb, wpb, WvT,
      q, k, U);

  big_kernel<<<dim3(3072), blk, 0, stream>>>(q, k, U, stb, sc, VWT,
      mbits, sums, scale);

  pvw_kernel<<<dim3(512), blk, 0, stream>>>(sc, VWT, sums, part);

  reduce4<<<dim3(2048), blk, 0, stream>>>(part, out);
}